// Round 11
// baseline (284.469 us; speedup 1.0000x reference)
//
#include <hip/hip_runtime.h>
#include <hip/hip_bf16.h>
#include <stdint.h>

typedef __attribute__((ext_vector_type(8))) short s16x8;
typedef __attribute__((ext_vector_type(4))) float f32x4;

#define DEVFN static __device__ __forceinline__

DEVFN unsigned short f2bf(float f) {
    union { float f; uint32_t u; } v; v.f = f;
    uint32_t u = v.u;
    uint32_t r = (u + 0x7fffu + ((u >> 16) & 1u)) >> 16;
    return (unsigned short)r;
}
DEVFN float bf2f(unsigned short h) {
    union { uint32_t u; float f; } v; v.u = ((uint32_t)h) << 16;
    return v.f;
}
DEVFN float bfu_lo(uint32_t v) {
    union { uint32_t u; float f; } c; c.u = v << 16; return c.f;
}
DEVFN float bfu_hi(uint32_t v) {
    union { uint32_t u; float f; } c; c.u = v & 0xffff0000u; return c.f;
}
DEVFN uint32_t cvtpk(float lo, float hi) {
    uint32_t r;
    asm("v_cvt_pk_bf16_f32 %0, %1, %2" : "=v"(r) : "v"(lo), "v"(hi));
    return r;
}

DEVFN void gload16(const void* g, void* l) {
    __builtin_amdgcn_global_load_lds(
        (const __attribute__((address_space(1))) unsigned int*)(uintptr_t)g,
        (__attribute__((address_space(3))) unsigned int*)(uint32_t)(uintptr_t)l,
        16, 0, 0);
}

DEVFN f32x4 mfma16(s16x8 a, s16x8 b, f32x4 c) {
    return __builtin_amdgcn_mfma_f32_16x16x32_bf16(a, b, c, 0, 0, 0);
}

// swizzled fragment read: tile rows are 128 B; XOR row-bits into 16B-slot bits
DEVFN s16x8 ldfrag(const unsigned short* base, int row, int cb) {
    return *(const s16x8*)((const char*)base + row * 128 + (cb ^ ((row & 7) << 4)));
}

// ---------------------------------------------------------------- prep (fused convert_cat + remap)
__global__ __launch_bounds__(256) void k_prep(const float* __restrict__ mems,
                                              const float* __restrict__ w,
                                              const float* __restrict__ r_emb,
                                              const float* __restrict__ r_bias,
                                              unsigned short* __restrict__ catb,
                                              unsigned short* __restrict__ rb,
                                              float* __restrict__ rbt) {
    long long tid0 = (long long)blockIdx.x * blockDim.x + threadIdx.x;
    long long stride = (long long)gridDim.x * blockDim.x;
    // cat = [mems; w] : 8192 x 1024 fp32 -> bf16
    for (long long i = tid0; i < 2097152; i += stride) {
        float4 v = (i < 1048576) ? ((const float4*)mems)[i] : ((const float4*)w)[i - 1048576];
        ushort4 o = make_ushort4(f2bf(v.x), f2bf(v.y), f2bf(v.z), f2bf(v.w));
        ((ushort4*)catb)[i] = o;
    }
    // r_emb (2048,16,64) -> rb [n][jj][d] bf16
    for (long long o = tid0; o < 2097152; o += stride) {
        int n = (int)(o >> 17);
        int jj = (int)((o >> 6) & 2047);
        int d = (int)(o & 63);
        rb[o] = f2bf(r_emb[((size_t)jj * 16 + n) * 64 + d]);
    }
    // r_bias (2048,16) -> rbt [n][jj] f32
    for (long long o = tid0; o < 32768; o += stride)
        rbt[o] = r_bias[(size_t)(o & 2047) * 16 + (o >> 11)];
}

// in fp32 [R][C] -> out bf16 [C][R]
__global__ __launch_bounds__(256) void k_transpose_convert(const float* __restrict__ in,
                                                           unsigned short* __restrict__ out,
                                                           int R, int C) {
    __shared__ float T[32][33];
    int c0 = blockIdx.x * 32, r0 = blockIdx.y * 32;
    int tx = threadIdx.x, ty = threadIdx.y;  // (32,8)
#pragma unroll
    for (int i = 0; i < 4; ++i) {
        int r = ty * 4 + i;
        T[r][tx] = in[(size_t)(r0 + r) * C + c0 + tx];
    }
    __syncthreads();
#pragma unroll
    for (int i = 0; i < 4; ++i) {
        int r = ty * 4 + i;
        out[(size_t)(c0 + r) * R + r0 + tx] = f2bf(T[tx][r]);
    }
}

// vb [bn][j][d] -> vt [bn][d][j]  (bf16, 64x64 tiles)
__global__ __launch_bounds__(256) void k_vtrans(const unsigned short* __restrict__ vb,
                                                unsigned short* __restrict__ vt) {
    __shared__ unsigned short T[64][72];
    int bn = blockIdx.y;
    int j0 = blockIdx.x * 64;
    int tid = threadIdx.x;
    int r = tid >> 2, cq = (tid & 3) * 16;
    size_t base = (size_t)bn * 131072;
    const unsigned short* src = vb + base + (size_t)(j0 + r) * 64 + cq;
    *(s16x8*)&T[r][cq] = *(const s16x8*)src;
    *(s16x8*)&T[r][cq + 8] = *(const s16x8*)(src + 8);
    __syncthreads();
    int d = r, jq = cq;
    s16x8 o0, o1;
#pragma unroll
    for (int t = 0; t < 8; ++t) { o0[t] = (short)T[jq + t][d]; o1[t] = (short)T[jq + 8 + t][d]; }
    unsigned short* dst = vt + base + (size_t)d * 2048 + j0 + jq;
    *(s16x8*)dst = o0;
    *(s16x8*)(dst + 8) = o1;
}

// ---------------------------------------------------------------- GEMM
// C = A(M x K, bf16 row-major) * B^T, B given transposed [N][K] bf16.
// 128x128 tile, BK=64, 4 waves (2x2), swizzled LDS. m_base/n_base offset the
// tile grid (GEMM1 is split: KV-part covers all rows x cols[1024,3072);
// Q-part covers rows[4096,8192) x cols[0,1024) -- mem-row Q output is dead).
template <int MODE>
__global__ __launch_bounds__(256) void k_gemm(const unsigned short* __restrict__ A,
                                              const unsigned short* __restrict__ B,
                                              int K, int N, int m_base, int n_base,
                                              const float* __restrict__ wres,
                                              float* __restrict__ outf,
                                              unsigned short* __restrict__ qb,
                                              unsigned short* __restrict__ kb,
                                              unsigned short* __restrict__ vb) {
    __shared__ unsigned short As[128 * 64];
    __shared__ unsigned short Bs[128 * 64];
    int tid = threadIdx.x, lane = tid & 63, wid = tid >> 6;
    int l15 = lane & 15, l16 = lane >> 4;
    int m0 = m_base + blockIdx.y * 128, n0 = n_base + blockIdx.x * 128;
    int wr = wid >> 1, wc = wid & 1;
    f32x4 acc[4][4];
#pragma unroll
    for (int a = 0; a < 4; ++a)
#pragma unroll
        for (int b = 0; b < 4; ++b) acc[a][b] = f32x4{0.f, 0.f, 0.f, 0.f};

    for (int k0 = 0; k0 < K; k0 += 64) {
        __syncthreads();
#pragma unroll
        for (int it = 0; it < 4; ++it) {
            int slot = it * 4 + wid;
            int elem = slot * 512 + lane * 8;
            int row = elem >> 6;
            int colb = (lane & 7) * 16;
            int scol = (colb ^ ((row & 7) << 4)) >> 1;
            gload16(A + (size_t)(m0 + row) * K + k0 + scol, (char*)As + (size_t)slot * 1024);
            gload16(B + (size_t)(n0 + row) * K + k0 + scol, (char*)Bs + (size_t)slot * 1024);
        }
        asm volatile("s_waitcnt vmcnt(0)" ::: "memory");
        __syncthreads();
#pragma unroll
        for (int kc = 0; kc < 2; ++kc) {
            s16x8 af[4], bfr[4];
#pragma unroll
            for (int f = 0; f < 4; ++f)
                af[f] = ldfrag(As, wr * 64 + f * 16 + l15, kc * 64 + l16 * 16);
#pragma unroll
            for (int f = 0; f < 4; ++f)
                bfr[f] = ldfrag(Bs, wc * 64 + f * 16 + l15, kc * 64 + l16 * 16);
#pragma unroll
            for (int fm = 0; fm < 4; ++fm)
#pragma unroll
                for (int fn = 0; fn < 4; ++fn)
                    acc[fm][fn] = mfma16(af[fm], bfr[fn], acc[fm][fn]);
        }
    }
#pragma unroll
    for (int fm = 0; fm < 4; ++fm)
#pragma unroll
        for (int fn = 0; fn < 4; ++fn)
#pragma unroll
            for (int r = 0; r < 4; ++r) {
                int row = m0 + wr * 64 + fm * 16 + l16 * 4 + r;
                int col = n0 + wc * 64 + fn * 16 + l15;
                float v = acc[fm][fn][r];
                if (MODE == 0) {
                    int t = row >> 2, bb = row & 3;
                    if (col < 1024) {
                        if (t >= 1024) {
                            int nn = col >> 6, d = col & 63;
                            qb[((size_t)(bb * 16 + nn) * 1024 + (t - 1024)) * 64 + d] = f2bf(v);
                        }
                    } else if (col < 2048) {
                        int c2 = col - 1024, nn = c2 >> 6, d = c2 & 63;
                        kb[((size_t)(bb * 16 + nn) * 2048 + t) * 64 + d] = f2bf(v);
                    } else {
                        int c2 = col - 2048, nn = c2 >> 6, d = c2 & 63;
                        vb[((size_t)(bb * 16 + nn) * 2048 + t) * 64 + d] = f2bf(v);
                    }
                } else {
                    size_t o = (size_t)row * N + col;
                    outf[o] = v + wres[o];
                }
            }
}

// ---------------------------------------------------------------- attention
// r10 base (paired i-tiles, skewed El stride-20, Ps stride-68) with:
//  * Rs = 192-row TRI-buffer: prefetch always writes the region no wave reads
//    this iter -> SINGLE barrier per iter; prefetch issues right after AC.
//  * Ps aliased into the El pool (same __shared__ array -> may-alias ordering;
//    per-wave DS ops are in-order; all El reads precede Ps writes).
//  * row-sum ls via mfma(pa, ones) in PV (replaces 16 VALU adds + end reduce).
__global__ __launch_bounds__(256) void k_attn(const unsigned short* __restrict__ qb,
                                              const unsigned short* __restrict__ kb,
                                              const unsigned short* __restrict__ vt,
                                              const unsigned short* __restrict__ rb,
                                              const float* __restrict__ rbt,
                                              const float* __restrict__ r_w_bias,
                                              unsigned short* __restrict__ av) {
    __shared__ unsigned short Ks[2][4096];   // [buf][jf][d] swizzled   16 KB
    __shared__ unsigned short Vs[2][4096];   // [buf][d][jf] swizzled   16 KB
    __shared__ unsigned short Rs[192 * 64];  // tri-buffer, swizzled    24 KB
    __shared__ unsigned short Elp[4][1920];  // El pool (Ps aliased)    15 KB
    __shared__ float rbs[192];               // tri-buffer band bias   .75 KB

    const float SC = 0.18033688f;  // 0.125 * log2(e)
    int tid = threadIdx.x, lane = tid & 63, wid = tid >> 6;
    int l15 = lane & 15, l16 = lane >> 4;
    int qr0 = l16 * 4;
    int bn = blockIdx.y, b = bn >> 4, n = bn & 15;
    size_t bq = (size_t)bn * 65536;
    size_t bk = (size_t)bn * 131072;
    int rbase = 48 - wid * 16;              // wave band-window start offset
    int lrow = lane >> 3;                   // dest row within an 8-row group
    int colb = (lane & 7) * 16;             // dest byte col
    int scolE = (colb ^ (lrow << 4)) >> 1;  // swizzled source col (elements)

    // loop-invariant LDS addresses (all further offsets are immediates)
    unsigned short* ElW = &Elp[wid][20 * l15 + 21 * qr0];          // + fe*320 + r*21
    const unsigned short* ElR = &Elp[wid][20 * (l15 + 15) + qr0];  // + fn*320, b64
    unsigned short* PsW = &Elp[wid][qr0 * 68 + l15];               // + fn*16 + r*68
    const unsigned short* PsR = &Elp[wid][l15 * 68];               // + kc*32 + l16*8

    s16x8 ones;
#pragma unroll
    for (int t = 0; t < 8; ++t) ones[t] = (short)0x3F80;  // bf16 1.0

    for (int h = 0; h < 2; ++h) {
        int it8 = h ? 15 - (int)blockIdx.x : (int)blockIdx.x;
        int i0 = it8 * 64;
        int njt = it8 + 17;
        int jjb = 960 - i0;  // band base: jj = jjb + j0 + rbase + bcol

        // Q fragments (pre-scaled by SC)
        s16x8 aq[2], aqr[2];
        {
            int qrow = i0 + wid * 16 + l15;
#pragma unroll
            for (int kc = 0; kc < 2; ++kc) {
                s16x8 qv = *(const s16x8*)(qb + bq + (size_t)qrow * 64 + kc * 32 + l16 * 8);
                s16x8 q1, q2;
#pragma unroll
                for (int t = 0; t < 8; ++t) {
                    float f = bf2f((unsigned short)qv[t]);
                    float rw = r_w_bias[n * 64 + kc * 32 + l16 * 8 + t];
                    q1[t] = (short)f2bf(f * SC);
                    q2[t] = (short)f2bf((f + rw) * SC);
                }
                aq[kc] = q1;
                aqr[kc] = q2;
            }
        }

        float m_[4];
        f32x4 accO[4], accL;
#pragma unroll
        for (int r = 0; r < 4; ++r) m_[r] = -3.0e38f;
#pragma unroll
        for (int f = 0; f < 4; ++f) accO[f] = f32x4{0.f, 0.f, 0.f, 0.f};
        accL = f32x4{0.f, 0.f, 0.f, 0.f};

        // ---- prologue: K/V tile 0, R band rows [0,128), rbs ----
#pragma unroll
        for (int q = 0; q < 2; ++q) {
            int s = wid * 2 + q;
            int row = s * 8 + lrow;
            gload16(kb + bk + (size_t)row * 64 + scolE, (char*)Ks[0] + s * 1024);
            gload16(vt + bk + (size_t)row * 2048 + scolE, (char*)Vs[0] + s * 1024);
        }
#pragma unroll
        for (int q = 0; q < 4; ++q) {
            int s = wid * 4 + q;
            int jju = jjb + s * 8 + lrow;  // <= 1087, no clamp needed
            gload16(rb + (size_t)n * 131072 + (size_t)jju * 64 + scolE,
                    (char*)Rs + (s * 8) * 128);
        }
        if (tid < 128) {
            int jju = jjb + tid;
            rbs[tid] = SC * rbt[(size_t)n * 2048 + jju];
        }
        __syncthreads();

        int cur = 0, rsb = 0;
        for (int jt = 0; jt < njt; ++jt) {
            int j0 = jt * 64;
            int jjc = jjb + j0;
            bool pf = (jt + 1 < njt);

            // E = q . R_window^T (16x80/wave) -> skewed El, rbias+mask folded
            __builtin_amdgcn_s_setprio(1);
#pragma unroll
            for (int fe = 0; fe < 5; ++fe) {
                int row = rsb + rbase + fe * 16 + l15;  // logical o in [0,128)
                if (row >= 192) row -= 192;
                f32x4 e = f32x4{0.f, 0.f, 0.f, 0.f};
                e = mfma16(aq[0], ldfrag(Rs, row, l16 * 16), e);
                e = mfma16(aq[1], ldfrag(Rs, row, 64 + l16 * 16), e);
                float rbv = rbs[row];
                uint32_t p01 = cvtpk(e[0] + rbv, e[1] + rbv);
                uint32_t p23 = cvtpk(e[2] + rbv, e[3] + rbv);
                ElW[fe * 320] = (unsigned short)p01;
                ElW[fe * 320 + 21] = (unsigned short)(p01 >> 16);
                ElW[fe * 320 + 42] = (unsigned short)p23;
                ElW[fe * 320 + 63] = (unsigned short)(p23 >> 16);
            }
            // AC = (q + r_w_bias) . K^T
            f32x4 sAC[4];
#pragma unroll
            for (int fn = 0; fn < 4; ++fn) {
                f32x4 a = f32x4{0.f, 0.f, 0.f, 0.f};
#pragma unroll
                for (int kc = 0; kc < 2; ++kc)
                    a = mfma16(aqr[kc], ldfrag(Ks[cur], fn * 16 + l15, kc * 64 + l16 * 16), a);
                sAC[fn] = a;
            }
            __builtin_amdgcn_s_setprio(0);

            // prefetch issue (flies under softmax + PV + barrier):
            // K/V into [cur^1]; R rows [jjc+128,+192) -> tri-region; rbs same
            if (pf) {
                int j0n = j0 + 64;
#pragma unroll
                for (int q = 0; q < 2; ++q) {
                    int s = wid * 2 + q;
                    int row = s * 8 + lrow;
                    gload16(kb + bk + (size_t)(j0n + row) * 64 + scolE,
                            (char*)Ks[cur ^ 1] + s * 1024);
                    gload16(vt + bk + (size_t)row * 2048 + j0n + scolE,
                            (char*)Vs[cur ^ 1] + s * 1024);
                }
#pragma unroll
                for (int q = 0; q < 2; ++q) {
                    int s = wid * 2 + q;
                    int w = rsb + 128 + s * 8;
                    if (w >= 192) w -= 192;
                    int jju = jjc + 128 + s * 8 + lrow;
                    int jja = jju > 2047 ? 2047 : jju;  // clamp source only
                    gload16(rb + (size_t)n * 131072 + (size_t)jja * 64 + scolE,
                            (char*)Rs + w * 128);
                }
                if (tid < 64) {
                    int w = rsb + 128 + tid;
                    if (w >= 192) w -= 192;
                    int jju = jjc + 128 + tid;
                    rbs[w] = (jju <= 2047) ? SC * rbt[(size_t)n * 2048 + jju] : -1.0e30f;
                }
            }

            // softmax: scores via 4x b64 diagonal reads; defer-max
            float pe[4][4];
            float lmax[4] = {-3.0e38f, -3.0e38f, -3.0e38f, -3.0e38f};
#pragma unroll
            for (int fn = 0; fn < 4; ++fn) {
                uint2 ev = *(const uint2*)(ElR + fn * 320);
                float e0 = bfu_lo(ev.x), e1 = bfu_hi(ev.x);
                float e2 = bfu_lo(ev.y), e3 = bfu_hi(ev.y);
                pe[fn][0] = sAC[fn][0] + e0;
                pe[fn][1] = sAC[fn][1] + e1;
                pe[fn][2] = sAC[fn][2] + e2;
                pe[fn][3] = sAC[fn][3] + e3;
#pragma unroll
                for (int r = 0; r < 4; ++r) lmax[r] = fmaxf(lmax[r], pe[fn][r]);
            }
            bool need = (lmax[0] > m_[0]) | (lmax[1] > m_[1]) | (lmax[2] > m_[2]) |
                        (lmax[3] > m_[3]);
            if (__any(need)) {
#pragma unroll
                for (int msk = 1; msk <= 8; msk <<= 1)
#pragma unroll
                    for (int r = 0; r < 4; ++r)
                        lmax[r] = fmaxf(lmax[r], __shfl_xor(lmax[r], msk, 64));
#pragma unroll
                for (int r = 0; r < 4; ++r) {
                    float mn = fmaxf(m_[r], lmax[r]);
                    float alpha = __builtin_exp2f(m_[r] - mn);
                    m_[r] = mn;
                    accL[r] *= alpha;
#pragma unroll
                    for (int f = 0; f < 4; ++f) accO[f][r] *= alpha;
                }
            }
            // all El reads above complete before these aliased Ps writes
#pragma unroll
            for (int fn = 0; fn < 4; ++fn) {
                float e0 = __builtin_exp2f(pe[fn][0] - m_[0]);
                float e1 = __builtin_exp2f(pe[fn][1] - m_[1]);
                float e2 = __builtin_exp2f(pe[fn][2] - m_[2]);
                float e3 = __builtin_exp2f(pe[fn][3] - m_[3]);
                uint32_t a = cvtpk(e0, e1);
                uint32_t c = cvtpk(e2, e3);
                PsW[fn * 16] = (unsigned short)a;
                PsW[fn * 16 + 68] = (unsigned short)(a >> 16);
                PsW[fn * 16 + 136] = (unsigned short)c;
                PsW[fn * 16 + 204] = (unsigned short)(c >> 16);
            }

            // PV (+ row-sum via ones-MFMA); Ps rows 8B-aligned -> 2x b64
            __builtin_amdgcn_s_setprio(1);
#pragma unroll
            for (int kc = 0; kc < 2; ++kc) {
                const uint2* pp = (const uint2*)(PsR + kc * 32 + l16 * 8);
                union { uint2 u2[2]; s16x8 v; } uu;
                uu.u2[0] = pp[0];
                uu.u2[1] = pp[1];
                s16x8 pa = uu.v;
                accL = mfma16(pa, ones, accL);
#pragma unroll
                for (int fd = 0; fd < 4; ++fd)
                    accO[fd] = mfma16(pa, ldfrag(Vs[cur], fd * 16 + l15, kc * 64 + l16 * 16),
                                      accO[fd]);
            }
            __builtin_amdgcn_s_setprio(0);

            __syncthreads();  // single barrier: drains prefetch, publishes all buffers
            cur ^= 1;
            rsb += 64;
            if (rsb == 192) rsb = 0;
        }

        // write attn_vec row-normalized, bf16, layout [i*4+b][n*64+d]
        // accL[r] = full row-sum (MFMA reduces across all lanes' k-slices)
#pragma unroll
        for (int r = 0; r < 4; ++r) {
            float inv = 1.f / accL[r];
            int ig = i0 + wid * 16 + qr0 + r;
#pragma unroll
            for (int fd = 0; fd < 4; ++fd)
                av[((size_t)ig * 4 + b) * 1024 + n * 64 + fd * 16 + l15] = f2bf(accO[fd][r] * inv);
        }
    }
}

// ---------------------------------------------------------------- layernorm (in-place on d_out)
__global__ __launch_bounds__(256) void k_ln(float* __restrict__ y, const float* __restrict__ g,
                                            const float* __restrict__ bta) {
    int row = blockIdx.x, tid = threadIdx.x;
    int lane = tid & 63, wid = tid >> 6;
    float4 v = ((const float4*)(y + (size_t)row * 1024))[tid];
    float s = v.x + v.y + v.z + v.w;
    float sq = v.x * v.x + v.y * v.y + v.z * v.z + v.w * v.w;
#pragma unroll
    for (int msk = 1; msk <= 32; msk <<= 1) {
        s += __shfl_xor(s, msk, 64);
        sq += __shfl_xor(sq, msk, 64);
    }
    __shared__ float red[2][4];
    if (lane == 0) { red[0][wid] = s; red[1][wid] = sq; }
    __syncthreads();
    s = red[0][0] + red[0][1] + red[0][2] + red[0][3];
    sq = red[1][0] + red[1][1] + red[1][2] + red[1][3];
    float mu = s * (1.f / 1024.f);
    float var = sq * (1.f / 1024.f) - mu * mu;
    float rs = rsqrtf(var + 1e-5f);
    float4 gv = ((const float4*)g)[tid];
    float4 bv = ((const float4*)bta)[tid];
    float4 o;
    o.x = (v.x - mu) * rs * gv.x + bv.x;
    o.y = (v.y - mu) * rs * gv.y + bv.y;
    o.z = (v.z - mu) * rs * gv.z + bv.z;
    o.w = (v.w - mu) * rs * gv.w + bv.w;
    ((float4*)(y + (size_t)row * 1024))[tid] = o;
}

// ---------------------------------------------------------------- launch
extern "C" void kernel_launch(void* const* d_in, const int* in_sizes, int n_in,
                              void* d_out, int out_size, void* d_ws, size_t ws_size,
                              hipStream_t stream) {
    const float* w      = (const float*)d_in[0];
    const float* mems   = (const float*)d_in[1];
    const float* r_emb  = (const float*)d_in[2];
    const float* r_wb   = (const float*)d_in[3];
    const float* r_bias = (const float*)d_in[4];
    const float* Wqkv   = (const float*)d_in[5];
    const float* Wo     = (const float*)d_in[6];
    const float* ln_g   = (const float*)d_in[7];
    const float* ln_b   = (const float*)d_in[8];
    float* out = (float*)d_out;

    char* p = (char*)d_ws;
    auto alloc = [&](size_t bytes) {
        char* q = p;
        p += (bytes + 255) & ~(size_t)255;
        return q;
    };
    unsigned short* catb  = (unsigned short*)alloc(8192ull * 1024 * 2);      // 16 MB
    unsigned short* wqkvT = (unsigned short*)alloc(3072ull * 1024 * 2);      // 6 MB
    unsigned short* woT   = (unsigned short*)alloc(1024ull * 1024 * 2);      // 2 MB
    unsigned short* rb    = (unsigned short*)alloc(16ull * 2048 * 64 * 2);   // 4 MB
    float*          rbt   = (float*)alloc(16ull * 2048 * 4);                 // 128 KB
    unsigned short* qbuf  = (unsigned short*)alloc(64ull * 1024 * 64 * 2);   // 8 MB
    unsigned short* kbuf  = (unsigned short*)alloc(64ull * 2048 * 64 * 2);   // 16 MB
    unsigned short* vbuf  = (unsigned short*)alloc(64ull * 2048 * 64 * 2);   // 16 MB
    unsigned short* av    = (unsigned short*)alloc(4096ull * 1024 * 2);      // 8 MB
    unsigned short* vtb = catb;  // catb dead after GEMM1

    k_prep<<<2048, 256, 0, stream>>>(mems, w, r_emb, r_bias, catb, rb, rbt);
    dim3 tb(32, 8);
    k_transpose_convert<<<dim3(96, 32), tb, 0, stream>>>(Wqkv, wqkvT, 1024, 3072);
    k_transpose_convert<<<dim3(32, 32), tb, 0, stream>>>(Wo, woT, 1024, 1024);

    // GEMM1 split: KV-part (all rows x cols[1024,3072)); Q-part (rows[4096,8192) x cols[0,1024))
    k_gemm<0><<<dim3(16, 64), 256, 0, stream>>>(catb, wqkvT, 1024, 3072, 0, 1024,
                                                nullptr, nullptr, qbuf, kbuf, vbuf);
    k_gemm<0><<<dim3(8, 32), 256, 0, stream>>>(catb, wqkvT, 1024, 3072, 4096, 0,
                                               nullptr, nullptr, qbuf, kbuf, vbuf);
    k_vtrans<<<dim3(32, 64), 256, 0, stream>>>(vbuf, vtb);
    k_attn<<<dim3(8, 64), 256, 0, stream>>>(qbuf, kbuf, vtb, rb, rbt, r_wb, av);
    k_gemm<1><<<dim3(8, 32), 256, 0, stream>>>(av, woT, 1024, 1024, 0, 0,
                                               w, out, nullptr, nullptr, nullptr);
    k_ln<<<4096, 256, 0, stream>>>(out, ln_g, ln_b);
}

// Round 12
// 242.854 us; speedup vs baseline: 1.1714x; 1.1714x over previous
//
#include <hip/hip_runtime.h>
#include <hip/hip_bf16.h>
#include <stdint.h>

typedef __attribute__((ext_vector_type(8))) short s16x8;
typedef __attribute__((ext_vector_type(4))) float f32x4;

#define DEVFN static __device__ __forceinline__

DEVFN unsigned short f2bf(float f) {
    union { float f; uint32_t u; } v; v.f = f;
    uint32_t u = v.u;
    uint32_t r = (u + 0x7fffu + ((u >> 16) & 1u)) >> 16;
    return (unsigned short)r;
}
DEVFN float bf2f(unsigned short h) {
    union { uint32_t u; float f; } v; v.u = ((uint32_t)h) << 16;
    return v.f;
}
DEVFN float bfu_lo(uint32_t v) {
    union { uint32_t u; float f; } c; c.u = v << 16; return c.f;
}
DEVFN float bfu_hi(uint32_t v) {
    union { uint32_t u; float f; } c; c.u = v & 0xffff0000u; return c.f;
}
DEVFN uint32_t cvtpk(float lo, float hi) {
    uint32_t r;
    asm("v_cvt_pk_bf16_f32 %0, %1, %2" : "=v"(r) : "v"(lo), "v"(hi));
    return r;
}

DEVFN void gload16(const void* g, void* l) {
    __builtin_amdgcn_global_load_lds(
        (const __attribute__((address_space(1))) unsigned int*)(uintptr_t)g,
        (__attribute__((address_space(3))) unsigned int*)(uint32_t)(uintptr_t)l,
        16, 0, 0);
}

DEVFN f32x4 mfma16(s16x8 a, s16x8 b, f32x4 c) {
    return __builtin_amdgcn_mfma_f32_16x16x32_bf16(a, b, c, 0, 0, 0);
}

// swizzled fragment read: tile rows are 128 B; XOR row-bits into 16B-slot bits
DEVFN s16x8 ldfrag(const unsigned short* base, int row, int cb) {
    return *(const s16x8*)((const char*)base + row * 128 + (cb ^ ((row & 7) << 4)));
}

// ---------------------------------------------------------------- converts
__global__ __launch_bounds__(256) void k_convert_cat(const float* __restrict__ mems,
                                                     const float* __restrict__ w,
                                                     unsigned short* __restrict__ catb) {
    const long long total4 = 2097152;  // 8M elems / 4
    for (long long i = (long long)blockIdx.x * blockDim.x + threadIdx.x; i < total4;
         i += (long long)gridDim.x * blockDim.x) {
        float4 v = (i < 1048576) ? ((const float4*)mems)[i] : ((const float4*)w)[i - 1048576];
        ushort4 o = make_ushort4(f2bf(v.x), f2bf(v.y), f2bf(v.z), f2bf(v.w));
        ((ushort4*)catb)[i] = o;
    }
}

// in fp32 [R][C] -> out bf16 [C][R]
__global__ __launch_bounds__(256) void k_transpose_convert(const float* __restrict__ in,
                                                           unsigned short* __restrict__ out,
                                                           int R, int C) {
    __shared__ float T[32][33];
    int c0 = blockIdx.x * 32, r0 = blockIdx.y * 32;
    int tx = threadIdx.x, ty = threadIdx.y;  // (32,8)
#pragma unroll
    for (int i = 0; i < 4; ++i) {
        int r = ty * 4 + i;
        T[r][tx] = in[(size_t)(r0 + r) * C + c0 + tx];
    }
    __syncthreads();
#pragma unroll
    for (int i = 0; i < 4; ++i) {
        int r = ty * 4 + i;
        out[(size_t)(c0 + r) * R + r0 + tx] = f2bf(T[tx][r]);
    }
}

// r_emb (2048,16,64) fp32 -> rb [n][jj][d] bf16 ; also r_bias (2048,16) -> rbt [n][jj] f32
__global__ __launch_bounds__(256) void k_remap_remb(const float* __restrict__ r_emb,
                                                    const float* __restrict__ r_bias,
                                                    unsigned short* __restrict__ rb,
                                                    float* __restrict__ rbt) {
    const long long total = 2097152;
    long long tid0 = (long long)blockIdx.x * blockDim.x + threadIdx.x;
    long long stride = (long long)gridDim.x * blockDim.x;
    for (long long o = tid0; o < total; o += stride) {
        int n = (int)(o >> 17);
        int jj = (int)((o >> 6) & 2047);
        int d = (int)(o & 63);
        rb[o] = f2bf(r_emb[((size_t)jj * 16 + n) * 64 + d]);
    }
    for (long long o = tid0; o < 32768; o += stride)
        rbt[o] = r_bias[(size_t)(o & 2047) * 16 + (o >> 11)];
}

// vb [bn][j][d] -> vt [bn][d][j]  (bf16, 64x64 tiles)
__global__ __launch_bounds__(256) void k_vtrans(const unsigned short* __restrict__ vb,
                                                unsigned short* __restrict__ vt) {
    __shared__ unsigned short T[64][72];
    int bn = blockIdx.y;
    int j0 = blockIdx.x * 64;
    int tid = threadIdx.x;
    int r = tid >> 2, cq = (tid & 3) * 16;
    size_t base = (size_t)bn * 131072;
    const unsigned short* src = vb + base + (size_t)(j0 + r) * 64 + cq;
    *(s16x8*)&T[r][cq] = *(const s16x8*)src;
    *(s16x8*)&T[r][cq + 8] = *(const s16x8*)(src + 8);
    __syncthreads();
    int d = r, jq = cq;
    s16x8 o0, o1;
#pragma unroll
    for (int t = 0; t < 8; ++t) { o0[t] = (short)T[jq + t][d]; o1[t] = (short)T[jq + 8 + t][d]; }
    unsigned short* dst = vt + base + (size_t)d * 2048 + j0 + jq;
    *(s16x8*)dst = o0;
    *(s16x8*)(dst + 8) = o1;
}

// ---------------------------------------------------------------- GEMM
// C = A(M x K, bf16 row-major) * B^T, B given transposed [N][K] bf16.
// 128x128 tile, BK=64, 4 waves (2x2), swizzled LDS.
// MODE 0 (QKV): 1D grid of 1280 blocks with dead-tile remap -- tiles
//   (rows<4096 x cols<1024) are the mem-row Q outputs (dead, sliced away by
//   the reference) and are skipped:
//     bid < 1024 : row-tile = bid>>4,      col-tile = 8 + (bid&15)   (K/V)
//     bid >= 1024: row-tile = 32+(q>>3),   col-tile = q&7            (Q live)
// MODE 1 (out proj): 2D grid as before, epilogue adds residual.
template <int MODE>
__global__ __launch_bounds__(256) void k_gemm(const unsigned short* __restrict__ A,
                                              const unsigned short* __restrict__ B,
                                              int K, int N,
                                              const float* __restrict__ wres,
                                              float* __restrict__ outf,
                                              unsigned short* __restrict__ qb,
                                              unsigned short* __restrict__ kb,
                                              unsigned short* __restrict__ vb) {
    __shared__ unsigned short As[128 * 64];
    __shared__ unsigned short Bs[128 * 64];
    int tid = threadIdx.x, lane = tid & 63, wid = tid >> 6;
    int l15 = lane & 15, l16 = lane >> 4;
    int m0, n0;
    if (MODE == 0) {
        int bid = blockIdx.x;
        if (bid < 1024) {
            m0 = (bid >> 4) * 128;
            n0 = (8 + (bid & 15)) * 128;
        } else {
            int q = bid - 1024;
            m0 = (32 + (q >> 3)) * 128;
            n0 = (q & 7) * 128;
        }
    } else {
        m0 = blockIdx.y * 128;
        n0 = blockIdx.x * 128;
    }
    int wr = wid >> 1, wc = wid & 1;
    f32x4 acc[4][4];
#pragma unroll
    for (int a = 0; a < 4; ++a)
#pragma unroll
        for (int b = 0; b < 4; ++b) acc[a][b] = f32x4{0.f, 0.f, 0.f, 0.f};

    for (int k0 = 0; k0 < K; k0 += 64) {
        __syncthreads();
#pragma unroll
        for (int it = 0; it < 4; ++it) {
            int slot = it * 4 + wid;
            int elem = slot * 512 + lane * 8;
            int row = elem >> 6;
            int colb = (lane & 7) * 16;
            int scol = (colb ^ ((row & 7) << 4)) >> 1;
            gload16(A + (size_t)(m0 + row) * K + k0 + scol, (char*)As + (size_t)slot * 1024);
            gload16(B + (size_t)(n0 + row) * K + k0 + scol, (char*)Bs + (size_t)slot * 1024);
        }
        asm volatile("s_waitcnt vmcnt(0)" ::: "memory");
        __syncthreads();
#pragma unroll
        for (int kc = 0; kc < 2; ++kc) {
            s16x8 af[4], bfr[4];
#pragma unroll
            for (int f = 0; f < 4; ++f)
                af[f] = ldfrag(As, wr * 64 + f * 16 + l15, kc * 64 + l16 * 16);
#pragma unroll
            for (int f = 0; f < 4; ++f)
                bfr[f] = ldfrag(Bs, wc * 64 + f * 16 + l15, kc * 64 + l16 * 16);
#pragma unroll
            for (int fm = 0; fm < 4; ++fm)
#pragma unroll
                for (int fn = 0; fn < 4; ++fn)
                    acc[fm][fn] = mfma16(af[fm], bfr[fn], acc[fm][fn]);
        }
    }
#pragma unroll
    for (int fm = 0; fm < 4; ++fm)
#pragma unroll
        for (int fn = 0; fn < 4; ++fn)
#pragma unroll
            for (int r = 0; r < 4; ++r) {
                int row = m0 + wr * 64 + fm * 16 + l16 * 4 + r;
                int col = n0 + wc * 64 + fn * 16 + l15;
                float v = acc[fm][fn][r];
                if (MODE == 0) {
                    int t = row >> 2, bb = row & 3;
                    if (col < 1024) {
                        if (t >= 1024) {
                            int nn = col >> 6, d = col & 63;
                            qb[((size_t)(bb * 16 + nn) * 1024 + (t - 1024)) * 64 + d] = f2bf(v);
                        }
                    } else if (col < 2048) {
                        int c2 = col - 1024, nn = c2 >> 6, d = c2 & 63;
                        kb[((size_t)(bb * 16 + nn) * 2048 + t) * 64 + d] = f2bf(v);
                    } else {
                        int c2 = col - 2048, nn = c2 >> 6, d = c2 & 63;
                        vb[((size_t)(bb * 16 + nn) * 2048 + t) * 64 + d] = f2bf(v);
                    }
                } else {
                    size_t o = (size_t)row * N + col;
                    outf[o] = v + wres[o];
                }
            }
}

// ---------------------------------------------------------------- attention
// r11 structure (paired i-tiles, tri-buffer Rs, single barrier, skewed El,
// Ps aliased into El pool, ls via ones-MFMA) + T13 defer-max THR=8:
// rescale only when lmax > m_ + 8 (log2 domain; P bounded by 2^8=256, safe in
// bf16/f32). Rescales become rare -> saves 16 shfl + rescale VALU most iters.
__global__ __launch_bounds__(256) void k_attn(const unsigned short* __restrict__ qb,
                                              const unsigned short* __restrict__ kb,
                                              const unsigned short* __restrict__ vt,
                                              const unsigned short* __restrict__ rb,
                                              const float* __restrict__ rbt,
                                              const float* __restrict__ r_w_bias,
                                              unsigned short* __restrict__ av) {
    __shared__ unsigned short Ks[2][4096];   // [buf][jf][d] swizzled   16 KB
    __shared__ unsigned short Vs[2][4096];   // [buf][d][jf] swizzled   16 KB
    __shared__ unsigned short Rs[192 * 64];  // tri-buffer, swizzled    24 KB
    __shared__ unsigned short Elp[4][1920];  // El pool (Ps aliased)    15 KB
    __shared__ float rbs[192];               // tri-buffer band bias   .75 KB

    const float SC = 0.18033688f;  // 0.125 * log2(e)
    int tid = threadIdx.x, lane = tid & 63, wid = tid >> 6;
    int l15 = lane & 15, l16 = lane >> 4;
    int qr0 = l16 * 4;
    int bn = blockIdx.y, b = bn >> 4, n = bn & 15;
    size_t bq = (size_t)bn * 65536;
    size_t bk = (size_t)bn * 131072;
    int rbase = 48 - wid * 16;              // wave band-window start offset
    int lrow = lane >> 3;                   // dest row within an 8-row group
    int colb = (lane & 7) * 16;             // dest byte col
    int scolE = (colb ^ (lrow << 4)) >> 1;  // swizzled source col (elements)

    // loop-invariant LDS addresses (all further offsets are immediates)
    unsigned short* ElW = &Elp[wid][20 * l15 + 21 * qr0];          // + fe*320 + r*21
    const unsigned short* ElR = &Elp[wid][20 * (l15 + 15) + qr0];  // + fn*320, b64
    unsigned short* PsW = &Elp[wid][qr0 * 68 + l15];               // + fn*16 + r*68
    const unsigned short* PsR = &Elp[wid][l15 * 68];               // + kc*32 + l16*8

    s16x8 ones;
#pragma unroll
    for (int t = 0; t < 8; ++t) ones[t] = (short)0x3F80;  // bf16 1.0

    for (int h = 0; h < 2; ++h) {
        int it8 = h ? 15 - (int)blockIdx.x : (int)blockIdx.x;
        int i0 = it8 * 64;
        int njt = it8 + 17;
        int jjb = 960 - i0;  // band base: jj = jjb + j0 + rbase + bcol

        // Q fragments (pre-scaled by SC)
        s16x8 aq[2], aqr[2];
        {
            int qrow = i0 + wid * 16 + l15;
#pragma unroll
            for (int kc = 0; kc < 2; ++kc) {
                s16x8 qv = *(const s16x8*)(qb + bq + (size_t)qrow * 64 + kc * 32 + l16 * 8);
                s16x8 q1, q2;
#pragma unroll
                for (int t = 0; t < 8; ++t) {
                    float f = bf2f((unsigned short)qv[t]);
                    float rw = r_w_bias[n * 64 + kc * 32 + l16 * 8 + t];
                    q1[t] = (short)f2bf(f * SC);
                    q2[t] = (short)f2bf((f + rw) * SC);
                }
                aq[kc] = q1;
                aqr[kc] = q2;
            }
        }

        float m_[4];
        f32x4 accO[4], accL;
#pragma unroll
        for (int r = 0; r < 4; ++r) m_[r] = -3.0e38f;
#pragma unroll
        for (int f = 0; f < 4; ++f) accO[f] = f32x4{0.f, 0.f, 0.f, 0.f};
        accL = f32x4{0.f, 0.f, 0.f, 0.f};

        // ---- prologue: K/V tile 0, R band rows [0,128), rbs ----
#pragma unroll
        for (int q = 0; q < 2; ++q) {
            int s = wid * 2 + q;
            int row = s * 8 + lrow;
            gload16(kb + bk + (size_t)row * 64 + scolE, (char*)Ks[0] + s * 1024);
            gload16(vt + bk + (size_t)row * 2048 + scolE, (char*)Vs[0] + s * 1024);
        }
#pragma unroll
        for (int q = 0; q < 4; ++q) {
            int s = wid * 4 + q;
            int jju = jjb + s * 8 + lrow;  // <= 1087, no clamp needed
            gload16(rb + (size_t)n * 131072 + (size_t)jju * 64 + scolE,
                    (char*)Rs + (s * 8) * 128);
        }
        if (tid < 128) {
            int jju = jjb + tid;
            rbs[tid] = SC * rbt[(size_t)n * 2048 + jju];
        }
        __syncthreads();

        int cur = 0, rsb = 0;
        for (int jt = 0; jt < njt; ++jt) {
            int j0 = jt * 64;
            int jjc = jjb + j0;
            bool pf = (jt + 1 < njt);

            // E = q . R_window^T (16x80/wave) -> skewed El, rbias+mask folded
            __builtin_amdgcn_s_setprio(1);
#pragma unroll
            for (int fe = 0; fe < 5; ++fe) {
                int row = rsb + rbase + fe * 16 + l15;
                if (row >= 192) row -= 192;
                f32x4 e = f32x4{0.f, 0.f, 0.f, 0.f};
                e = mfma16(aq[0], ldfrag(Rs, row, l16 * 16), e);
                e = mfma16(aq[1], ldfrag(Rs, row, 64 + l16 * 16), e);
                float rbv = rbs[row];
                uint32_t p01 = cvtpk(e[0] + rbv, e[1] + rbv);
                uint32_t p23 = cvtpk(e[2] + rbv, e[3] + rbv);
                ElW[fe * 320] = (unsigned short)p01;
                ElW[fe * 320 + 21] = (unsigned short)(p01 >> 16);
                ElW[fe * 320 + 42] = (unsigned short)p23;
                ElW[fe * 320 + 63] = (unsigned short)(p23 >> 16);
            }
            // AC = (q + r_w_bias) . K^T
            f32x4 sAC[4];
#pragma unroll
            for (int fn = 0; fn < 4; ++fn) {
                f32x4 a = f32x4{0.f, 0.f, 0.f, 0.f};
#pragma unroll
                for (int kc = 0; kc < 2; ++kc)
                    a = mfma16(aqr[kc], ldfrag(Ks[cur], fn * 16 + l15, kc * 64 + l16 * 16), a);
                sAC[fn] = a;
            }
            __builtin_amdgcn_s_setprio(0);

            // prefetch issue (flies under softmax + PV + barrier)
            if (pf) {
                int j0n = j0 + 64;
#pragma unroll
                for (int q = 0; q < 2; ++q) {
                    int s = wid * 2 + q;
                    int row = s * 8 + lrow;
                    gload16(kb + bk + (size_t)(j0n + row) * 64 + scolE,
                            (char*)Ks[cur ^ 1] + s * 1024);
                    gload16(vt + bk + (size_t)row * 2048 + j0n + scolE,
                            (char*)Vs[cur ^ 1] + s * 1024);
                }
#pragma unroll
                for (int q = 0; q < 2; ++q) {
                    int s = wid * 2 + q;
                    int w = rsb + 128 + s * 8;
                    if (w >= 192) w -= 192;
                    int jju = jjc + 128 + s * 8 + lrow;
                    int jja = jju > 2047 ? 2047 : jju;  // clamp source only
                    gload16(rb + (size_t)n * 131072 + (size_t)jja * 64 + scolE,
                            (char*)Rs + w * 128);
                }
                if (tid < 64) {
                    int w = rsb + 128 + tid;
                    if (w >= 192) w -= 192;
                    int jju = jjc + 128 + tid;
                    rbs[w] = (jju <= 2047) ? SC * rbt[(size_t)n * 2048 + jju] : -1.0e30f;
                }
            }

            // softmax: scores via 4x b64 diagonal reads; defer-max THR=8
            float pe[4][4];
            float lmax[4] = {-3.0e38f, -3.0e38f, -3.0e38f, -3.0e38f};
#pragma unroll
            for (int fn = 0; fn < 4; ++fn) {
                uint2 ev = *(const uint2*)(ElR + fn * 320);
                float e0 = bfu_lo(ev.x), e1 = bfu_hi(ev.x);
                float e2 = bfu_lo(ev.y), e3 = bfu_hi(ev.y);
                pe[fn][0] = sAC[fn][0] + e0;
                pe[fn][1] = sAC[fn][1] + e1;
                pe[fn][2] = sAC[fn][2] + e2;
                pe[fn][3] = sAC[fn][3] + e3;
#pragma unroll
                for (int r = 0; r < 4; ++r) lmax[r] = fmaxf(lmax[r], pe[fn][r]);
            }
            bool need = (lmax[0] > m_[0] + 8.f) | (lmax[1] > m_[1] + 8.f) |
                        (lmax[2] > m_[2] + 8.f) | (lmax[3] > m_[3] + 8.f);
            if (__any(need)) {
#pragma unroll
                for (int msk = 1; msk <= 8; msk <<= 1)
#pragma unroll
                    for (int r = 0; r < 4; ++r)
                        lmax[r] = fmaxf(lmax[r], __shfl_xor(lmax[r], msk, 64));
#pragma unroll
                for (int r = 0; r < 4; ++r) {
                    float mn = fmaxf(m_[r], lmax[r]);
                    float alpha = __builtin_exp2f(m_[r] - mn);
                    m_[r] = mn;
                    accL[r] *= alpha;
#pragma unroll
                    for (int f = 0; f < 4; ++f) accO[f][r] *= alpha;
                }
            }
            // all El reads above complete before these aliased Ps writes
#pragma unroll
            for (int fn = 0; fn < 4; ++fn) {
                float e0 = __builtin_exp2f(pe[fn][0] - m_[0]);
                float e1 = __builtin_exp2f(pe[fn][1] - m_[1]);
                float e2 = __builtin_exp2f(pe[fn][2] - m_[2]);
                float e3 = __builtin_exp2f(pe[fn][3] - m_[3]);
                uint32_t a = cvtpk(e0, e1);
                uint32_t c = cvtpk(e2, e3);
                PsW[fn * 16] = (unsigned short)a;
                PsW[fn * 16 + 68] = (unsigned short)(a >> 16);
                PsW[fn * 16 + 136] = (unsigned short)c;
                PsW[fn * 16 + 204] = (unsigned short)(c >> 16);
            }

            // PV (+ row-sum via ones-MFMA); Ps rows 8B-aligned -> 2x b64
            __builtin_amdgcn_s_setprio(1);
#pragma unroll
            for (int kc = 0; kc < 2; ++kc) {
                const uint2* pp = (const uint2*)(PsR + kc * 32 + l16 * 8);
                union { uint2 u2[2]; s16x8 v; } uu;
                uu.u2[0] = pp[0];
                uu.u2[1] = pp[1];
                s16x8 pa = uu.v;
                accL = mfma16(pa, ones, accL);
#pragma unroll
                for (int fd = 0; fd < 4; ++fd)
                    accO[fd] = mfma16(pa, ldfrag(Vs[cur], fd * 16 + l15, kc * 64 + l16 * 16),
                                      accO[fd]);
            }
            __builtin_amdgcn_s_setprio(0);

            __syncthreads();  // single barrier: drains prefetch, publishes all buffers
            cur ^= 1;
            rsb += 64;
            if (rsb == 192) rsb = 0;
        }

        // write attn_vec row-normalized, bf16, layout [i*4+b][n*64+d]
#pragma unroll
        for (int r = 0; r < 4; ++r) {
            float inv = 1.f / accL[r];
            int ig = i0 + wid * 16 + qr0 + r;
#pragma unroll
            for (int fd = 0; fd < 4; ++fd)
                av[((size_t)ig * 4 + b) * 1024 + n * 64 + fd * 16 + l15] = f2bf(accO[fd][r] * inv);
        }
    }
}

// ---------------------------------------------------------------- layernorm (in-place on d_out)
__global__ __launch_bounds__(256) void k_ln(float* __restrict__ y, const float* __restrict__ g,
                                            const float* __restrict__ bta) {
    int row = blockIdx.x, tid = threadIdx.x;
    int lane = tid & 63, wid = tid >> 6;
    float4 v = ((const float4*)(y + (size_t)row * 1024))[tid];
    float s = v.x + v.y + v.z + v.w;
    float sq = v.x * v.x + v.y * v.y + v.z * v.z + v.w * v.w;
#pragma unroll
    for (int msk = 1; msk <= 32; msk <<= 1) {
        s += __shfl_xor(s, msk, 64);
        sq += __shfl_xor(sq, msk, 64);
    }
    __shared__ float red[2][4];
    if (lane == 0) { red[0][wid] = s; red[1][wid] = sq; }
    __syncthreads();
    s = red[0][0] + red[0][1] + red[0][2] + red[0][3];
    sq = red[1][0] + red[1][1] + red[1][2] + red[1][3];
    float mu = s * (1.f / 1024.f);
    float var = sq * (1.f / 1024.f) - mu * mu;
    float rs = rsqrtf(var + 1e-5f);
    float4 gv = ((const float4*)g)[tid];
    float4 bv = ((const float4*)bta)[tid];
    float4 o;
    o.x = (v.x - mu) * rs * gv.x + bv.x;
    o.y = (v.y - mu) * rs * gv.y + bv.y;
    o.z = (v.z - mu) * rs * gv.z + bv.z;
    o.w = (v.w - mu) * rs * gv.w + bv.w;
    ((float4*)(y + (size_t)row * 1024))[tid] = o;
}

// ---------------------------------------------------------------- launch
extern "C" void kernel_launch(void* const* d_in, const int* in_sizes, int n_in,
                              void* d_out, int out_size, void* d_ws, size_t ws_size,
                              hipStream_t stream) {
    const float* w      = (const float*)d_in[0];
    const float* mems   = (const float*)d_in[1];
    const float* r_emb  = (const float*)d_in[2];
    const float* r_wb   = (const float*)d_in[3];
    const float* r_bias = (const float*)d_in[4];
    const float* Wqkv   = (const float*)d_in[5];
    const float* Wo     = (const float*)d_in[6];
    const float* ln_g   = (const float*)d_in[7];
    const float* ln_b   = (const float*)d_in[8];
    float* out = (float*)d_out;

    char* p = (char*)d_ws;
    auto alloc = [&](size_t bytes) {
        char* q = p;
        p += (bytes + 255) & ~(size_t)255;
        return q;
    };
    unsigned short* catb  = (unsigned short*)alloc(8192ull * 1024 * 2);      // 16 MB
    unsigned short* wqkvT = (unsigned short*)alloc(3072ull * 1024 * 2);      // 6 MB
    unsigned short* woT   = (unsigned short*)alloc(1024ull * 1024 * 2);      // 2 MB
    unsigned short* rb    = (unsigned short*)alloc(16ull * 2048 * 64 * 2);   // 4 MB
    float*          rbt   = (float*)alloc(16ull * 2048 * 4);                 // 128 KB
    unsigned short* qbuf  = (unsigned short*)alloc(64ull * 1024 * 64 * 2);   // 8 MB
    unsigned short* kbuf  = (unsigned short*)alloc(64ull * 2048 * 64 * 2);   // 16 MB
    unsigned short* vbuf  = (unsigned short*)alloc(64ull * 2048 * 64 * 2);   // 16 MB
    unsigned short* av    = (unsigned short*)alloc(4096ull * 1024 * 2);      // 8 MB
    unsigned short* vtb = catb;  // catb dead after GEMM1

    k_convert_cat<<<2048, 256, 0, stream>>>(mems, w, catb);
    dim3 tb(32, 8);
    k_transpose_convert<<<dim3(96, 32), tb, 0, stream>>>(Wqkv, wqkvT, 1024, 3072);
    k_transpose_convert<<<dim3(32, 32), tb, 0, stream>>>(Wo, woT, 1024, 1024);
    k_remap_remb<<<2048, 256, 0, stream>>>(r_emb, r_bias, rb, rbt);

    // GEMM1: 1280 blocks, dead-tile-skipping remap (mem-row Q tiles skipped)
    k_gemm<0><<<1280, 256, 0, stream>>>(catb, wqkvT, 1024, 3072,
                                        nullptr, nullptr, qbuf, kbuf, vbuf);
    k_vtrans<<<dim3(32, 64), 256, 0, stream>>>(vbuf, vtb);
    k_attn<<<dim3(8, 64), 256, 0, stream>>>(qbuf, kbuf, vtb, rb, rbt, r_wb, av);
    k_gemm<1><<<dim3(8, 32), 256, 0, stream>>>(av, woT, 1024, 1024,
                                               w, out, nullptr, nullptr, nullptr);
    k_ln<<<4096, 256, 0, stream>>>(out, ln_g, ln_b);
}